// Round 8
// baseline (509.644 us; speedup 1.0000x reference)
//
#include <hip/hip_runtime.h>
#include <hip/hip_bf16.h>
#include <hip/hip_cooperative_groups.h>

namespace cg = cooperative_groups;

// LoRA-GCN: out = propagate(x @ W_B^T @ W_A^T) + bias
// Rank-3 fusion: propagate z = x @ W_B^T (N x 3), apply W_A^T after.
// R8: single persistent cooperative kernel (1024 blocks). Phase A: R6 binning
//     (CHUNK 4096, proven) + work-stealing zproj on ALL blocks; grid.sync;
//     Phase B: deg->zw SPLIT=4 (full machine); grid.sync; Phase C: agg+out
//     SPLIT=4. Kills 3 dispatch drains + idle-CU phases. Fallback = R6 path.

#define RANK 3
#define IN_DIM 256
#define OUT_DIM 64

#define NB    256         // sub-buckets
#define BS    392         // nodes per sub-bucket (256*392 = 100352 >= N), < 512
#define QS    98          // quarter sub-bucket (SPLIT=4)
#define CAP2  8192        // per-sub-bucket record capacity (avg ~6.1k, +34%)
#define CHUNK 4096        // edges per binning block (16 per thread @256) - R6 proven
#define GRID  1024        // cooperative grid (4 blocks/CU)
#define GRAB  8           // zproj groups per work-steal grab

// ---------------------------------------------------------------------------
// R8 cooperative kernel: all phases, 256 threads/block, GRID blocks.
__global__ void __launch_bounds__(256, 4) kcoop(
        const float* __restrict__ x, const float* __restrict__ WB,
        const int* __restrict__ idx, const float* __restrict__ WA,
        const float* __restrict__ bias, float* __restrict__ out,
        int N, int E, int nbin, int ngroups, int nsample,
        float4* __restrict__ z4, float4* __restrict__ zw,
        unsigned* __restrict__ recs, int* __restrict__ gcur,
        int* __restrict__ zctr) {
    __shared__ int s_hist[NB];
    __shared__ int s_lbase[NB];
    __shared__ int s_base[NB];
    __shared__ int s_rank[NB];
    __shared__ int s_wsum[4];
    __shared__ int s_nz;
    __shared__ int s_grab;
    __shared__ unsigned s_buf[CHUNK];
    __shared__ int s_deg[QS];
    __shared__ float s_agg[QS * 3];
    __shared__ float s_wa0[64], s_wa1[64], s_wa2[64], s_bb[64];

    const int bid = blockIdx.x;
    const int tid = threadIdx.x;
    cg::grid_group grid = cg::this_grid();

    // ================= Phase A: bin (blocks < nbin) then zproj (all) ========
    if (bid < nbin) {
        // in-block layout detect (R6-proven; L2-hot after first block)
        if (tid == 0) s_nz = 0;
        __syncthreads();
        int nz = 0;
        for (int i = tid; i < nsample; i += 256) nz |= idx[2 * i + 1];
        if (nz) s_nz = 1;                   // benign race
        __syncthreads();
        const int stride = (s_nz == 0) ? 2 : 1;
        const int* rowp = idx;
        const int* colp = idx + (size_t)E * stride;

        for (int cb = bid; cb < nbin; cb += GRID) {
            { int t = tid; s_hist[t] = 0; s_rank[t] = 0; }   // blockDim == NB
            const int e0 = cb * CHUNK;
            __syncthreads();

            int er[16], ec[16];
            #pragma unroll
            for (int k = 0; k < 16; ++k) {
                int e = e0 + k * 256 + tid;
                er[k] = 0; ec[k] = 0;        // sentinel r==c -> skipped
                if (e < E) {
                    if (stride == 2) {
                        er[k] = reinterpret_cast<const int2*>(rowp)[e].x;
                        ec[k] = reinterpret_cast<const int2*>(colp)[e].x;
                    } else {
                        er[k] = rowp[e];
                        ec[k] = colp[e];
                    }
                }
            }
            #pragma unroll
            for (int k = 0; k < 16; ++k)
                if (er[k] != ec[k]) atomicAdd(&s_hist[ec[k] / BS], 1);
            __syncthreads();

            // 256-entry exclusive scan (4-wave shuffle + cross-wave offsets)
            {
                int t = tid;
                int v = s_hist[t];
                int incl = v;
                #pragma unroll
                for (int d = 1; d < 64; d <<= 1) {
                    int o = __shfl_up(incl, d);
                    if ((t & 63) >= d) incl += o;
                }
                if ((t & 63) == 63) s_wsum[t >> 6] = incl;
                __syncthreads();
                int woff = 0;
                #pragma unroll
                for (int w = 0; w < 4; ++w) if (w < (t >> 6)) woff += s_wsum[w];
                s_lbase[t] = woff + incl - v;
                s_base[t]  = v ? atomicAdd(&gcur[t], v) : 0;
            }
            __syncthreads();

            #pragma unroll
            for (int k = 0; k < 16; ++k) {
                if (er[k] != ec[k]) {
                    int b = ec[k] / BS;
                    int pos = s_lbase[b] + atomicAdd(&s_rank[b], 1);
                    s_buf[pos] = ((unsigned)er[k] << 9) | (unsigned)(ec[k] - b * BS);
                }
            }
            __syncthreads();

            int total = s_lbase[NB - 1] + s_hist[NB - 1];
            for (int i = tid; i < total; i += 256) {
                int lo = 0, hi = NB - 1;
                #pragma unroll
                for (int s = 0; s < 8; ++s) {
                    int mid = (lo + hi + 1) >> 1;
                    if (s_lbase[mid] <= i) lo = mid; else hi = mid - 1;
                }
                int rel = s_base[lo] + (i - s_lbase[lo]);
                if (rel < CAP2)
                    recs[(size_t)lo * CAP2 + rel] = s_buf[i];
            }
            __syncthreads();
        }
    }

    // work-stealing zproj: one wave per node, GRAB groups (4 nodes each) per grab
    {
        const int lane = tid & 63;
        const int wv = tid >> 6;
        float4 w0 = reinterpret_cast<const float4*>(WB)[lane];
        float4 w1 = reinterpret_cast<const float4*>(WB + IN_DIM)[lane];
        float4 w2 = reinterpret_cast<const float4*>(WB + 2 * IN_DIM)[lane];
        for (;;) {
            __syncthreads();
            if (tid == 0) s_grab = atomicAdd(zctr, GRAB);
            __syncthreads();
            int g0 = s_grab;
            if (g0 >= ngroups) break;
            #pragma unroll
            for (int k = 0; k < GRAB; ++k) {
                int g = g0 + k;
                if (g >= ngroups) break;
                int node = g * 4 + wv;
                if (node >= N) continue;
                const float4* xr = reinterpret_cast<const float4*>(x + (size_t)node * IN_DIM);
                float4 xv = xr[lane];
                float p0 = xv.x * w0.x + xv.y * w0.y + xv.z * w0.z + xv.w * w0.w;
                float p1 = xv.x * w1.x + xv.y * w1.y + xv.z * w1.z + xv.w * w1.w;
                float p2 = xv.x * w2.x + xv.y * w2.y + xv.z * w2.z + xv.w * w2.w;
                #pragma unroll
                for (int m = 32; m > 0; m >>= 1) {
                    p0 += __shfl_xor(p0, m);
                    p1 += __shfl_xor(p1, m);
                    p2 += __shfl_xor(p2, m);
                }
                if (lane == 0) z4[node] = make_float4(p0, p1, p2, 0.0f);
            }
        }
    }

    __threadfence();
    grid.sync();

    // ================= Phase B: deg -> zw (SPLIT=4, all blocks) =============
    {
        int sb = bid >> 2, q = bid & 3;
        if (sb < NB) {
            for (int j = tid; j < QS; j += 256) s_deg[j] = 0;
            __syncthreads();
            int cnt = gcur[sb]; if (cnt > CAP2) cnt = CAP2;
            const unsigned* rb = recs + (size_t)sb * CAP2;
            int lo = q * QS;
            for (int i = tid; i < cnt; i += 256) {
                unsigned d = (rb[i] & 511u) - (unsigned)lo;
                if (d < (unsigned)QS) atomicAdd(&s_deg[d], 1);
            }
            __syncthreads();
            if (tid < QS) {
                int n = sb * BS + lo + tid;
                if (n < N) {
                    float di = rsqrtf((float)s_deg[tid] + 1.0f);
                    float4 zn = z4[n];
                    zw[n] = make_float4(di * zn.x, di * zn.y, di * zn.z, di);
                }
            }
        }
    }

    __threadfence();
    grid.sync();

    // ================= Phase C: agg + epilogue + store (SPLIT=4) ============
    {
        int sb = bid >> 2, q = bid & 3;
        if (sb < NB) {
            for (int j = tid; j < QS * 3; j += 256) s_agg[j] = 0.0f;
            if (tid < 64) {
                s_wa0[tid] = WA[tid * 3 + 0];
                s_wa1[tid] = WA[tid * 3 + 1];
                s_wa2[tid] = WA[tid * 3 + 2];
                s_bb[tid]  = bias[tid];
            }
            __syncthreads();
            int cnt = gcur[sb]; if (cnt > CAP2) cnt = CAP2;
            const unsigned* rb = recs + (size_t)sb * CAP2;
            int lo = q * QS;
            for (int i = tid; i < cnt; i += 256) {
                unsigned rc = rb[i];
                unsigned d = (rc & 511u) - (unsigned)lo;
                if (d < (unsigned)QS) {
                    float4 zr = zw[rc >> 9];
                    atomicAdd(&s_agg[d * 3 + 0], zr.x);
                    atomicAdd(&s_agg[d * 3 + 1], zr.y);
                    atomicAdd(&s_agg[d * 3 + 2], zr.z);
                }
            }
            __syncthreads();
            if (tid < QS) {
                int n = sb * BS + lo + tid;
                if (n < N) {
                    float4 zn = zw[n];
                    float di = zn.w;
                    s_agg[tid * 3 + 0] = di * (s_agg[tid * 3 + 0] + zn.x);
                    s_agg[tid * 3 + 1] = di * (s_agg[tid * 3 + 1] + zn.y);
                    s_agg[tid * 3 + 2] = di * (s_agg[tid * 3 + 2] + zn.z);
                }
            }
            __syncthreads();
            for (int i = tid; i < QS * 16; i += 256) {
                int nl = i >> 4, j4 = (i & 15) << 2;
                int n = sb * BS + lo + nl;
                if (n >= N) continue;
                float a0 = s_agg[nl * 3 + 0], a1 = s_agg[nl * 3 + 1], a2 = s_agg[nl * 3 + 2];
                float4 o;
                o.x = a0 * s_wa0[j4+0] + a1 * s_wa1[j4+0] + a2 * s_wa2[j4+0] + s_bb[j4+0];
                o.y = a0 * s_wa0[j4+1] + a1 * s_wa1[j4+1] + a2 * s_wa2[j4+1] + s_bb[j4+1];
                o.z = a0 * s_wa0[j4+2] + a1 * s_wa1[j4+2] + a2 * s_wa2[j4+2] + s_bb[j4+2];
                o.w = a0 * s_wa0[j4+3] + a1 * s_wa1[j4+3] + a2 * s_wa2[j4+3] + s_bb[j4+3];
                *reinterpret_cast<float4*>(out + (size_t)n * OUT_DIM + j4) = o;
            }
        }
    }
}

// ===========================================================================
// R6 4-dispatch fallback kernels (proven 77.8 us) + R1 shape-robust path.
// ===========================================================================
__global__ void k1_zproj_bin(const float* __restrict__ x,
                             const float* __restrict__ WB,
                             float4* __restrict__ z4, int N,
                             const int* __restrict__ idx, int E, int nsample,
                             unsigned* __restrict__ recs, int* __restrict__ gcur,
                             int nbin) {
    __shared__ int s_hist[NB];
    __shared__ int s_lbase[NB];
    __shared__ int s_base[NB];
    __shared__ int s_rank[NB];
    __shared__ int s_wsum[4];
    __shared__ int s_nz;
    __shared__ unsigned s_buf[CHUNK];

    if ((int)blockIdx.x < nbin) {
        if (threadIdx.x == 0) s_nz = 0;
        { int t = threadIdx.x; s_hist[t] = 0; s_rank[t] = 0; }
        __syncthreads();
        int nz = 0;
        for (int i = threadIdx.x; i < nsample; i += 256) nz |= idx[2 * i + 1];
        if (nz) s_nz = 1;
        __syncthreads();
        const int stride = (s_nz == 0) ? 2 : 1;
        const int* rowp = idx;
        const int* colp = idx + (size_t)E * stride;
        const int e0 = blockIdx.x * CHUNK;

        int er[16], ec[16];
        #pragma unroll
        for (int k = 0; k < 16; ++k) {
            int e = e0 + k * 256 + (int)threadIdx.x;
            er[k] = 0; ec[k] = 0;
            if (e < E) {
                if (stride == 2) {
                    er[k] = reinterpret_cast<const int2*>(rowp)[e].x;
                    ec[k] = reinterpret_cast<const int2*>(colp)[e].x;
                } else {
                    er[k] = rowp[e];
                    ec[k] = colp[e];
                }
            }
        }
        #pragma unroll
        for (int k = 0; k < 16; ++k)
            if (er[k] != ec[k]) atomicAdd(&s_hist[ec[k] / BS], 1);
        __syncthreads();
        {
            int t = threadIdx.x;
            int v = s_hist[t];
            int incl = v;
            #pragma unroll
            for (int d = 1; d < 64; d <<= 1) {
                int o = __shfl_up(incl, d);
                if ((t & 63) >= d) incl += o;
            }
            if ((t & 63) == 63) s_wsum[t >> 6] = incl;
            __syncthreads();
            int woff = 0;
            #pragma unroll
            for (int w = 0; w < 4; ++w) if (w < (t >> 6)) woff += s_wsum[w];
            s_lbase[t] = woff + incl - v;
            s_base[t]  = v ? atomicAdd(&gcur[t], v) : 0;
        }
        __syncthreads();
        #pragma unroll
        for (int k = 0; k < 16; ++k) {
            if (er[k] != ec[k]) {
                int b = ec[k] / BS;
                int pos = s_lbase[b] + atomicAdd(&s_rank[b], 1);
                s_buf[pos] = ((unsigned)er[k] << 9) | (unsigned)(ec[k] - b * BS);
            }
        }
        __syncthreads();
        int total = s_lbase[NB - 1] + s_hist[NB - 1];
        for (int i = threadIdx.x; i < total; i += 256) {
            int lo = 0, hi = NB - 1;
            #pragma unroll
            for (int s = 0; s < 8; ++s) {
                int mid = (lo + hi + 1) >> 1;
                if (s_lbase[mid] <= i) lo = mid; else hi = mid - 1;
            }
            int rel = s_base[lo] + (i - s_lbase[lo]);
            if (rel < CAP2)
                recs[(size_t)lo * CAP2 + rel] = s_buf[i];
        }
        return;
    }

    int gtid = (blockIdx.x - nbin) * blockDim.x + threadIdx.x;
    int node = gtid >> 6;
    int lane = threadIdx.x & 63;
    if (node >= N) return;
    const float4* xr = reinterpret_cast<const float4*>(x + (size_t)node * IN_DIM);
    float4 xv = xr[lane];
    float4 w0 = reinterpret_cast<const float4*>(WB)[lane];
    float4 w1 = reinterpret_cast<const float4*>(WB + IN_DIM)[lane];
    float4 w2 = reinterpret_cast<const float4*>(WB + 2 * IN_DIM)[lane];
    float p0 = xv.x * w0.x + xv.y * w0.y + xv.z * w0.z + xv.w * w0.w;
    float p1 = xv.x * w1.x + xv.y * w1.y + xv.z * w1.z + xv.w * w1.w;
    float p2 = xv.x * w2.x + xv.y * w2.y + xv.z * w2.z + xv.w * w2.w;
    #pragma unroll
    for (int m = 32; m > 0; m >>= 1) {
        p0 += __shfl_xor(p0, m);
        p1 += __shfl_xor(p1, m);
        p2 += __shfl_xor(p2, m);
    }
    if (lane == 0) z4[node] = make_float4(p0, p1, p2, 0.0f);
}

__global__ void __launch_bounds__(512) k2_zw(
        const unsigned* __restrict__ recs, const int* __restrict__ gcur,
        const float4* __restrict__ z4, float4* __restrict__ zw, int N) {
    __shared__ int s_deg[BS];
    int b = blockIdx.x;
    for (int j = threadIdx.x; j < BS; j += 512) s_deg[j] = 0;
    __syncthreads();
    int cnt = gcur[b]; if (cnt > CAP2) cnt = CAP2;
    const unsigned* rb = recs + (size_t)b * CAP2;
    for (int i = threadIdx.x; i < cnt; i += 512)
        atomicAdd(&s_deg[rb[i] & 511u], 1);
    __syncthreads();
    for (int j = threadIdx.x; j < BS; j += 512) {
        int n = b * BS + j;
        if (n >= N) break;
        float di = rsqrtf((float)s_deg[j] + 1.0f);
        float4 zn = z4[n];
        zw[n] = make_float4(di * zn.x, di * zn.y, di * zn.z, di);
    }
}

__global__ void __launch_bounds__(1024) k3_aggout(
        const unsigned* __restrict__ recs, const int* __restrict__ gcur,
        const float4* __restrict__ zw,
        const float* __restrict__ WA, const float* __restrict__ bias,
        float* __restrict__ out, int N) {
    __shared__ float s_agg[BS * 3];
    __shared__ float s_wa0[64], s_wa1[64], s_wa2[64], s_bb[64];
    int b = blockIdx.x;
    for (int j = threadIdx.x; j < BS * 3; j += 1024) s_agg[j] = 0.0f;
    if (threadIdx.x < 64) {
        int j = threadIdx.x;
        s_wa0[j] = WA[j * 3 + 0];
        s_wa1[j] = WA[j * 3 + 1];
        s_wa2[j] = WA[j * 3 + 2];
        s_bb[j]  = bias[j];
    }
    __syncthreads();
    int cnt = gcur[b]; if (cnt > CAP2) cnt = CAP2;
    const unsigned* rb = recs + (size_t)b * CAP2;
    for (int i = threadIdx.x; i < cnt; i += 1024) {
        unsigned rc = rb[i];
        int cl = (int)(rc & 511u);
        float4 zr = zw[rc >> 9];
        atomicAdd(&s_agg[cl * 3 + 0], zr.x);
        atomicAdd(&s_agg[cl * 3 + 1], zr.y);
        atomicAdd(&s_agg[cl * 3 + 2], zr.z);
    }
    __syncthreads();
    if (threadIdx.x < BS) {
        int n = b * BS + (int)threadIdx.x;
        if (n < N) {
            float4 zn = zw[n];
            float di = zn.w;
            s_agg[threadIdx.x * 3 + 0] = di * (s_agg[threadIdx.x * 3 + 0] + zn.x);
            s_agg[threadIdx.x * 3 + 1] = di * (s_agg[threadIdx.x * 3 + 1] + zn.y);
            s_agg[threadIdx.x * 3 + 2] = di * (s_agg[threadIdx.x * 3 + 2] + zn.z);
        }
    }
    __syncthreads();
    for (int i = threadIdx.x; i < BS * 16; i += 1024) {
        int nl = i >> 4, j4 = (i & 15) << 2;
        int n = b * BS + nl;
        if (n >= N) continue;
        float a0 = s_agg[nl * 3 + 0], a1 = s_agg[nl * 3 + 1], a2 = s_agg[nl * 3 + 2];
        float4 o;
        o.x = a0 * s_wa0[j4+0] + a1 * s_wa1[j4+0] + a2 * s_wa2[j4+0] + s_bb[j4+0];
        o.y = a0 * s_wa0[j4+1] + a1 * s_wa1[j4+1] + a2 * s_wa2[j4+1] + s_bb[j4+1];
        o.z = a0 * s_wa0[j4+2] + a1 * s_wa1[j4+2] + a2 * s_wa2[j4+2] + s_bb[j4+2];
        o.w = a0 * s_wa0[j4+3] + a1 * s_wa1[j4+3] + a2 * s_wa2[j4+3] + s_bb[j4+3];
        *reinterpret_cast<float4*>(out + (size_t)n * OUT_DIM + j4) = o;
    }
}

// R1 shape-robust fallback
__global__ void detect_kernel(const int* __restrict__ idx, int nsample, int* flag) {
    __shared__ int s_nz;
    if (threadIdx.x == 0) s_nz = 0;
    __syncthreads();
    int nz = 0;
    for (int i = threadIdx.x; i < nsample; i += blockDim.x) nz |= idx[2 * i + 1];
    if (nz) s_nz = 1;
    __syncthreads();
    if (threadIdx.x == 0) *flag = (s_nz == 0) ? 1 : 0;
}
__global__ void deg_kernel(const int* __restrict__ idx, int E,
                           const int* __restrict__ flag, float* __restrict__ deg) {
    int stride = (*flag) ? 2 : 1;
    const int* rowp = idx;
    const int* colp = idx + (size_t)E * stride;
    int step = gridDim.x * blockDim.x;
    for (int e = blockIdx.x * blockDim.x + threadIdx.x; e < E; e += step) {
        int r = rowp[(size_t)e * stride];
        int c = colp[(size_t)e * stride];
        if (r != c) atomicAdd(&deg[c], 1.0f);
    }
}
__global__ void dinv_self_kernel(const float4* __restrict__ z4, const float* __restrict__ deg,
                                 float* __restrict__ dinv, float* __restrict__ agg, int N) {
    int n = blockIdx.x * blockDim.x + threadIdx.x;
    if (n >= N) return;
    float d = deg[n] + 1.0f;
    float di = rsqrtf(d);
    dinv[n] = di;
    float w = 1.0f / d;
    float4 zn = z4[n];
    agg[(size_t)n * 3 + 0] = w * zn.x;
    agg[(size_t)n * 3 + 1] = w * zn.y;
    agg[(size_t)n * 3 + 2] = w * zn.z;
}
__global__ void scatter_kernel(const int* __restrict__ idx, int E,
                               const int* __restrict__ flag,
                               const float4* __restrict__ z4,
                               const float* __restrict__ dinv,
                               float* __restrict__ agg) {
    int stride = (*flag) ? 2 : 1;
    const int* rowp = idx;
    const int* colp = idx + (size_t)E * stride;
    int step = gridDim.x * blockDim.x;
    for (int e = blockIdx.x * blockDim.x + threadIdx.x; e < E; e += step) {
        int r = rowp[(size_t)e * stride];
        int c = colp[(size_t)e * stride];
        if (r != c) {
            float w = dinv[r] * dinv[c];
            float4 zr = z4[r];
            atomicAdd(&agg[(size_t)c * 3 + 0], w * zr.x);
            atomicAdd(&agg[(size_t)c * 3 + 1], w * zr.y);
            atomicAdd(&agg[(size_t)c * 3 + 2], w * zr.z);
        }
    }
}
__global__ void out_kernel(const float* __restrict__ agg,
                           const float* __restrict__ WA,
                           const float* __restrict__ bias,
                           float* __restrict__ out, int N) {
    int t = blockIdx.x * blockDim.x + threadIdx.x;
    int n = t >> 6;
    int j = t & 63;
    if (n >= N) return;
    float a0 = agg[(size_t)n * 3 + 0];
    float a1 = agg[(size_t)n * 3 + 1];
    float a2 = agg[(size_t)n * 3 + 2];
    out[(size_t)n * OUT_DIM + j] =
        a0 * WA[j * 3 + 0] + a1 * WA[j * 3 + 1] + a2 * WA[j * 3 + 2] + bias[j];
}

extern "C" void kernel_launch(void* const* d_in, const int* in_sizes, int n_in,
                              void* d_out, int out_size, void* d_ws, size_t ws_size,
                              hipStream_t stream) {
    const float* x    = (const float*)d_in[0];
    const int*   idx  = (const int*)d_in[1];
    const float* WB   = (const float*)d_in[2];
    const float* WA   = (const float*)d_in[3];
    const float* bias = (const float*)d_in[4];
    float* out = (float*)d_out;

    const int N = in_sizes[0] / IN_DIM;     // 100000
    const int E = in_sizes[1] / 2;          // 1600000

    auto align256 = [](size_t o) { return (o + 255) & ~(size_t)255; };
    char* ws = (char*)d_ws;
    size_t off = 0;
    int*    flag = (int*)(ws + off);    off = align256(off + sizeof(int));
    int*    gcur = (int*)(ws + off);    off = align256(off + (NB + 1) * sizeof(int));
    float4* z4   = (float4*)(ws + off); off = align256(off + (size_t)N * sizeof(float4));
    float4* zw   = (float4*)(ws + off); off = align256(off + (size_t)N * sizeof(float4));
    float*  dinv = (float*)(ws + off);  off = align256(off + (size_t)N * sizeof(float));
    unsigned* recs = (unsigned*)(ws + off); off = align256(off + (size_t)NB * CAP2 * sizeof(unsigned));
    int* zctr = gcur + NB;
    // fallback reuses fast-path regions
    float* degF = (float*)zw;
    float* aggF = (float*)recs;

    const bool fast = (N <= NB * BS) && (N < (1 << 23)) && (ws_size >= off);

    int nsample = E < 1024 ? E : 1024;

    if (fast) {
        hipMemsetAsync(gcur, 0, (NB + 1) * sizeof(int), stream);
        int nbin = (E + CHUNK - 1) / CHUNK;
        int ngroups = (N + 3) / 4;
        void* kargs[] = { (void*)&x, (void*)&WB, (void*)&idx, (void*)&WA,
                          (void*)&bias, (void*)&out, (void*)&N, (void*)&E,
                          (void*)&nbin, (void*)&ngroups, (void*)&nsample,
                          (void*)&z4, (void*)&zw, (void*)&recs, (void*)&gcur,
                          (void*)&zctr };
        hipError_t err = hipLaunchCooperativeKernel((void*)kcoop, dim3(GRID),
                                                    dim3(256), kargs, 0, stream);
        if (err != hipSuccess) {
            // R6 4-dispatch fallback (gcur already zeroed)
            int nzp = (N + 3) / 4;
            k1_zproj_bin<<<nbin + nzp, 256, 0, stream>>>(x, WB, z4, N, idx, E,
                                                         nsample, recs, gcur, nbin);
            k2_zw<<<NB, 512, 0, stream>>>(recs, gcur, z4, zw, N);
            k3_aggout<<<NB, 1024, 0, stream>>>(recs, gcur, zw, WA, bias, out, N);
        }
    } else {
        detect_kernel<<<1, 256, 0, stream>>>(idx, nsample, flag);
        k1_zproj_bin<<<(N + 3) / 4, 256, 0, stream>>>(x, WB, z4, N, idx, E,
                                                      nsample, (unsigned*)aggF, gcur, 0);
        hipMemsetAsync(degF, 0, (size_t)N * sizeof(float), stream);
        deg_kernel<<<2048, 256, 0, stream>>>(idx, E, flag, degF);
        dinv_self_kernel<<<(N + 255) / 256, 256, 0, stream>>>(z4, degF, dinv, aggF, N);
        scatter_kernel<<<2048, 256, 0, stream>>>(idx, E, flag, z4, dinv, aggF);
        long long total = (long long)N * OUT_DIM;
        out_kernel<<<(int)((total + 255) / 256), 256, 0, stream>>>(aggF, WA, bias, out, N);
    }
}

// Round 9
// 169.437 us; speedup vs baseline: 3.0079x; 3.0079x over previous
//
#include <hip/hip_runtime.h>
#include <hip/hip_bf16.h>

// LoRA-GCN: out = propagate(x @ W_B^T @ W_A^T) + bias
// Rank-3 fusion: propagate z = x @ W_B^T (N x 3), apply W_A^T after.
// R9: revert R8 coop (509us disaster: fixed 48% occupancy + grid.sync cost).
//     Back to R6 4-dispatch structure with ONE change: bin blocks interleaved
//     every S-th block among zproj blocks so bin latency hides under the
//     102 MB x-stream (R6 ran all 391 bin blocks first = HBM-idle prologue).

#define RANK 3
#define IN_DIM 256
#define OUT_DIM 64

#define NB    256         // sub-buckets
#define BS    392         // nodes per sub-bucket (256*392 = 100352 >= N), < 512
#define CAP2  8192        // per-sub-bucket record capacity (avg ~6.1k, +34%)
#define CHUNK 4096        // edges per binning block (16 per thread @256) - proven

// ---------------------------------------------------------------------------
// K1: fused zproj + bin, roles interleaved: block b is a BIN block iff
// (b % S == 0 && b/S < nbin), handling chunk q = b/S; otherwise zproj block
// zidx = b - min(ceil(b/S), nbin).
__global__ void k1_zproj_bin(const float* __restrict__ x,
                             const float* __restrict__ WB,     // [3][256]
                             float4* __restrict__ z4, int N,
                             const int* __restrict__ idx, int E, int nsample,
                             unsigned* __restrict__ recs, int* __restrict__ gcur,
                             int nbin, int S) {
    __shared__ int s_hist[NB];
    __shared__ int s_lbase[NB];
    __shared__ int s_base[NB];
    __shared__ int s_rank[NB];
    __shared__ int s_wsum[4];
    __shared__ int s_nz;
    __shared__ unsigned s_buf[CHUNK];

    const int b = blockIdx.x;
    const int q = b / S, r = b - q * S;

    if (r == 0 && q < nbin) {
        // ---- bin branch (chunk q) ----
        if (threadIdx.x == 0) s_nz = 0;
        { int t = threadIdx.x; s_hist[t] = 0; s_rank[t] = 0; }   // blockDim == NB
        __syncthreads();
        int nz = 0;
        for (int i = threadIdx.x; i < nsample; i += 256) nz |= idx[2 * i + 1];
        if (nz) s_nz = 1;                    // benign race
        __syncthreads();
        const int stride = (s_nz == 0) ? 2 : 1;
        const int* rowp = idx;
        const int* colp = idx + (size_t)E * stride;
        const int e0 = q * CHUNK;

        int er[16], ec[16];
        #pragma unroll
        for (int k = 0; k < 16; ++k) {
            int e = e0 + k * 256 + (int)threadIdx.x;
            er[k] = 0; ec[k] = 0;            // sentinel r==c -> skipped
            if (e < E) {
                if (stride == 2) {
                    er[k] = reinterpret_cast<const int2*>(rowp)[e].x;
                    ec[k] = reinterpret_cast<const int2*>(colp)[e].x;
                } else {
                    er[k] = rowp[e];
                    ec[k] = colp[e];
                }
            }
        }
        #pragma unroll
        for (int k = 0; k < 16; ++k)
            if (er[k] != ec[k]) atomicAdd(&s_hist[ec[k] / BS], 1);
        __syncthreads();

        // 256-entry exclusive scan: 4-wave shuffle scan + cross-wave offsets
        {
            int t = threadIdx.x;             // == bucket id
            int v = s_hist[t];
            int incl = v;
            #pragma unroll
            for (int d = 1; d < 64; d <<= 1) {
                int o = __shfl_up(incl, d);
                if ((t & 63) >= d) incl += o;
            }
            if ((t & 63) == 63) s_wsum[t >> 6] = incl;
            __syncthreads();
            int woff = 0;
            #pragma unroll
            for (int w = 0; w < 4; ++w) if (w < (t >> 6)) woff += s_wsum[w];
            s_lbase[t] = woff + incl - v;
            s_base[t]  = v ? atomicAdd(&gcur[t], v) : 0;
        }
        __syncthreads();

        #pragma unroll
        for (int k = 0; k < 16; ++k) {
            if (er[k] != ec[k]) {
                int bb = ec[k] / BS;
                int pos = s_lbase[bb] + atomicAdd(&s_rank[bb], 1);
                s_buf[pos] = ((unsigned)er[k] << 9) | (unsigned)(ec[k] - bb * BS);
            }
        }
        __syncthreads();

        int total = s_lbase[NB - 1] + s_hist[NB - 1];
        for (int i = threadIdx.x; i < total; i += 256) {
            int lo = 0, hi = NB - 1;         // largest bb with lbase[bb] <= i
            #pragma unroll
            for (int s = 0; s < 8; ++s) {
                int mid = (lo + hi + 1) >> 1;
                if (s_lbase[mid] <= i) lo = mid; else hi = mid - 1;
            }
            int rel = s_base[lo] + (i - s_lbase[lo]);
            if (rel < CAP2)
                recs[(size_t)lo * CAP2 + rel] = s_buf[i];
        }
        return;
    }

    // ---- zproj branch: one wave per node ----
    int nbefore = min((b + S - 1) / S, nbin);        // bin blocks before b
    int gtid = (b - nbefore) * blockDim.x + threadIdx.x;
    int node = gtid >> 6;
    int lane = threadIdx.x & 63;
    if (node >= N) return;

    const float4* xr = reinterpret_cast<const float4*>(x + (size_t)node * IN_DIM);
    float4 xv = xr[lane];
    float4 w0 = reinterpret_cast<const float4*>(WB)[lane];
    float4 w1 = reinterpret_cast<const float4*>(WB + IN_DIM)[lane];
    float4 w2 = reinterpret_cast<const float4*>(WB + 2 * IN_DIM)[lane];

    float p0 = xv.x * w0.x + xv.y * w0.y + xv.z * w0.z + xv.w * w0.w;
    float p1 = xv.x * w1.x + xv.y * w1.y + xv.z * w1.z + xv.w * w1.w;
    float p2 = xv.x * w2.x + xv.y * w2.y + xv.z * w2.z + xv.w * w2.w;

    #pragma unroll
    for (int m = 32; m > 0; m >>= 1) {
        p0 += __shfl_xor(p0, m);
        p1 += __shfl_xor(p1, m);
        p2 += __shfl_xor(p2, m);
    }
    if (lane == 0) z4[node] = make_float4(p0, p1, p2, 0.0f);
}

// ---------------------------------------------------------------------------
// K2: one block per sub-bucket: degree histogram from slab, then
// zw[n] = (dinv*z, dinv) with dinv = rsqrt(deg+1).
__global__ void __launch_bounds__(512) k2_zw(
        const unsigned* __restrict__ recs, const int* __restrict__ gcur,
        const float4* __restrict__ z4, float4* __restrict__ zw, int N) {
    __shared__ int s_deg[BS];
    int b = blockIdx.x;
    for (int j = threadIdx.x; j < BS; j += 512) s_deg[j] = 0;
    __syncthreads();
    int cnt = gcur[b]; if (cnt > CAP2) cnt = CAP2;
    const unsigned* rb = recs + (size_t)b * CAP2;
    for (int i = threadIdx.x; i < cnt; i += 512)
        atomicAdd(&s_deg[rb[i] & 511u], 1);
    __syncthreads();
    for (int j = threadIdx.x; j < BS; j += 512) {
        int n = b * BS + j;
        if (n >= N) break;
        float di = rsqrtf((float)s_deg[j] + 1.0f);
        float4 zn = z4[n];
        zw[n] = make_float4(di * zn.x, di * zn.y, di * zn.z, di);
    }
}

// ---------------------------------------------------------------------------
// K3: one block per sub-bucket. Scan OWN slab only, LDS-accumulate, fused
// epilogue: a = zw[n].w*(sum + zw[n].xyz); out[n][:] = a . W_A + bias.
__global__ void __launch_bounds__(1024) k3_aggout(
        const unsigned* __restrict__ recs, const int* __restrict__ gcur,
        const float4* __restrict__ zw,
        const float* __restrict__ WA,   // [64][3]
        const float* __restrict__ bias,
        float* __restrict__ out, int N) {
    __shared__ float s_agg[BS * 3];
    __shared__ float s_wa0[64], s_wa1[64], s_wa2[64], s_bb[64];
    int b = blockIdx.x;

    for (int j = threadIdx.x; j < BS * 3; j += 1024) s_agg[j] = 0.0f;
    if (threadIdx.x < 64) {
        int j = threadIdx.x;
        s_wa0[j] = WA[j * 3 + 0];
        s_wa1[j] = WA[j * 3 + 1];
        s_wa2[j] = WA[j * 3 + 2];
        s_bb[j]  = bias[j];
    }
    __syncthreads();

    int cnt = gcur[b]; if (cnt > CAP2) cnt = CAP2;
    const unsigned* rb = recs + (size_t)b * CAP2;
    for (int i = threadIdx.x; i < cnt; i += 1024) {
        unsigned rc = rb[i];
        int cl = (int)(rc & 511u);
        float4 zr = zw[rc >> 9];
        atomicAdd(&s_agg[cl * 3 + 0], zr.x);
        atomicAdd(&s_agg[cl * 3 + 1], zr.y);
        atomicAdd(&s_agg[cl * 3 + 2], zr.z);
    }
    __syncthreads();

    if (threadIdx.x < BS) {
        int n = b * BS + (int)threadIdx.x;
        if (n < N) {
            float4 zn = zw[n];
            float di = zn.w;
            s_agg[threadIdx.x * 3 + 0] = di * (s_agg[threadIdx.x * 3 + 0] + zn.x);
            s_agg[threadIdx.x * 3 + 1] = di * (s_agg[threadIdx.x * 3 + 1] + zn.y);
            s_agg[threadIdx.x * 3 + 2] = di * (s_agg[threadIdx.x * 3 + 2] + zn.z);
        }
    }
    __syncthreads();

    for (int i = threadIdx.x; i < BS * 16; i += 1024) {
        int nl = i >> 4, j4 = (i & 15) << 2;
        int n = b * BS + nl;
        if (n >= N) continue;
        float a0 = s_agg[nl * 3 + 0], a1 = s_agg[nl * 3 + 1], a2 = s_agg[nl * 3 + 2];
        float4 o;
        o.x = a0 * s_wa0[j4+0] + a1 * s_wa1[j4+0] + a2 * s_wa2[j4+0] + s_bb[j4+0];
        o.y = a0 * s_wa0[j4+1] + a1 * s_wa1[j4+1] + a2 * s_wa2[j4+1] + s_bb[j4+1];
        o.z = a0 * s_wa0[j4+2] + a1 * s_wa1[j4+2] + a2 * s_wa2[j4+2] + s_bb[j4+2];
        o.w = a0 * s_wa0[j4+3] + a1 * s_wa1[j4+3] + a2 * s_wa2[j4+3] + s_bb[j4+3];
        *reinterpret_cast<float4*>(out + (size_t)n * OUT_DIM + j4) = o;
    }
}

// ---------------------------------------------------------------------------
// Fallback (R1 path, shape-robust): detect + global-atomic deg/scatter + out.
__global__ void detect_kernel(const int* __restrict__ idx, int nsample, int* flag) {
    __shared__ int s_nz;
    if (threadIdx.x == 0) s_nz = 0;
    __syncthreads();
    int nz = 0;
    for (int i = threadIdx.x; i < nsample; i += blockDim.x) nz |= idx[2 * i + 1];
    if (nz) s_nz = 1;
    __syncthreads();
    if (threadIdx.x == 0) *flag = (s_nz == 0) ? 1 : 0;
}
__global__ void deg_kernel(const int* __restrict__ idx, int E,
                           const int* __restrict__ flag, float* __restrict__ deg) {
    int stride = (*flag) ? 2 : 1;
    const int* rowp = idx;
    const int* colp = idx + (size_t)E * stride;
    int step = gridDim.x * blockDim.x;
    for (int e = blockIdx.x * blockDim.x + threadIdx.x; e < E; e += step) {
        int r = rowp[(size_t)e * stride];
        int c = colp[(size_t)e * stride];
        if (r != c) atomicAdd(&deg[c], 1.0f);
    }
}
__global__ void dinv_self_kernel(const float4* __restrict__ z4, const float* __restrict__ deg,
                                 float* __restrict__ dinv, float* __restrict__ agg, int N) {
    int n = blockIdx.x * blockDim.x + threadIdx.x;
    if (n >= N) return;
    float d = deg[n] + 1.0f;
    float di = rsqrtf(d);
    dinv[n] = di;
    float w = 1.0f / d;
    float4 zn = z4[n];
    agg[(size_t)n * 3 + 0] = w * zn.x;
    agg[(size_t)n * 3 + 1] = w * zn.y;
    agg[(size_t)n * 3 + 2] = w * zn.z;
}
__global__ void scatter_kernel(const int* __restrict__ idx, int E,
                               const int* __restrict__ flag,
                               const float4* __restrict__ z4,
                               const float* __restrict__ dinv,
                               float* __restrict__ agg) {
    int stride = (*flag) ? 2 : 1;
    const int* rowp = idx;
    const int* colp = idx + (size_t)E * stride;
    int step = gridDim.x * blockDim.x;
    for (int e = blockIdx.x * blockDim.x + threadIdx.x; e < E; e += step) {
        int r = rowp[(size_t)e * stride];
        int c = colp[(size_t)e * stride];
        if (r != c) {
            float w = dinv[r] * dinv[c];
            float4 zr = z4[r];
            atomicAdd(&agg[(size_t)c * 3 + 0], w * zr.x);
            atomicAdd(&agg[(size_t)c * 3 + 1], w * zr.y);
            atomicAdd(&agg[(size_t)c * 3 + 2], w * zr.z);
        }
    }
}
__global__ void out_kernel(const float* __restrict__ agg,
                           const float* __restrict__ WA,
                           const float* __restrict__ bias,
                           float* __restrict__ out, int N) {
    int t = blockIdx.x * blockDim.x + threadIdx.x;
    int n = t >> 6;
    int j = t & 63;
    if (n >= N) return;
    float a0 = agg[(size_t)n * 3 + 0];
    float a1 = agg[(size_t)n * 3 + 1];
    float a2 = agg[(size_t)n * 3 + 2];
    out[(size_t)n * OUT_DIM + j] =
        a0 * WA[j * 3 + 0] + a1 * WA[j * 3 + 1] + a2 * WA[j * 3 + 2] + bias[j];
}

extern "C" void kernel_launch(void* const* d_in, const int* in_sizes, int n_in,
                              void* d_out, int out_size, void* d_ws, size_t ws_size,
                              hipStream_t stream) {
    const float* x    = (const float*)d_in[0];
    const int*   idx  = (const int*)d_in[1];
    const float* WB   = (const float*)d_in[2];
    const float* WA   = (const float*)d_in[3];
    const float* bias = (const float*)d_in[4];
    float* out = (float*)d_out;

    const int N = in_sizes[0] / IN_DIM;     // 100000
    const int E = in_sizes[1] / 2;          // 1600000

    auto align256 = [](size_t o) { return (o + 255) & ~(size_t)255; };
    char* ws = (char*)d_ws;
    size_t off = 0;
    int*    flag = (int*)(ws + off);    off = align256(off + sizeof(int));
    int*    gcur = (int*)(ws + off);    off = align256(off + NB * sizeof(int));
    float4* z4   = (float4*)(ws + off); off = align256(off + (size_t)N * sizeof(float4));
    float4* zw   = (float4*)(ws + off); off = align256(off + (size_t)N * sizeof(float4));
    float*  dinv = (float*)(ws + off);  off = align256(off + (size_t)N * sizeof(float));
    unsigned* recs = (unsigned*)(ws + off); off = align256(off + (size_t)NB * CAP2 * sizeof(unsigned));
    // fallback reuses fast-path regions
    float* degF = (float*)zw;
    float* aggF = (float*)recs;            // N*3 floats fit in recs region (8MB)

    const bool fast = (N <= NB * BS) && (N < (1 << 23)) && (ws_size >= off);

    int nsample = E < 1024 ? E : 1024;

    if (fast) {
        hipMemsetAsync(gcur, 0, NB * sizeof(int), stream);
        int nbin = (E + CHUNK - 1) / CHUNK;
        int nzp  = (N + 3) / 4;
        int S = (nbin + nzp) / nbin;        // interleave stride (~65)
        if (S < 1) S = 1;
        k1_zproj_bin<<<nbin + nzp, 256, 0, stream>>>(x, WB, z4, N, idx, E, nsample,
                                                     recs, gcur, nbin, S);
        k2_zw<<<NB, 512, 0, stream>>>(recs, gcur, z4, zw, N);
        k3_aggout<<<NB, 1024, 0, stream>>>(recs, gcur, zw, WA, bias, out, N);
    } else {
        detect_kernel<<<1, 256, 0, stream>>>(idx, nsample, flag);
        k1_zproj_bin<<<(N + 3) / 4, 256, 0, stream>>>(x, WB, z4, N, idx, E, nsample,
                                                      (unsigned*)aggF, gcur, 0, 1);
        hipMemsetAsync(degF, 0, (size_t)N * sizeof(float), stream);
        deg_kernel<<<2048, 256, 0, stream>>>(idx, E, flag, degF);
        dinv_self_kernel<<<(N + 255) / 256, 256, 0, stream>>>(z4, degF, dinv, aggF, N);
        scatter_kernel<<<2048, 256, 0, stream>>>(idx, E, flag, z4, dinv, aggF);
        long long total = (long long)N * OUT_DIM;
        out_kernel<<<(int)((total + 255) / 256), 256, 0, stream>>>(aggF, WA, bias, out, N);
    }
}

// Round 10
// 71.797 us; speedup vs baseline: 7.0984x; 2.3600x over previous
//
#include <hip/hip_runtime.h>
#include <hip/hip_bf16.h>

// LoRA-GCN: out = propagate(x @ W_B^T @ W_A^T) + bias
// Rank-3 fusion: propagate z = x @ W_B^T (N x 3), apply W_A^T after.
// R10: R6 structure restored (bin blocks first in fused K1 = best schedule,
//      77.8us). Single change: zproj uses 16-lane groups (quarter-wave):
//      3 DS shuffle ops/node instead of 18, 4 float4 loads/lane (256B
//      coalesced segments per group). R9 showed zproj is issue-bound, not
//      HBM-bound (L3 holds x; 472 GB/s at 11% VALU).

#define RANK 3
#define IN_DIM 256
#define OUT_DIM 64

#define NB    256         // sub-buckets
#define BS    392         // nodes per sub-bucket (256*392 = 100352 >= N), < 512
#define CAP2  8192        // per-sub-bucket record capacity (avg ~6.1k, +34%)
#define CHUNK 4096        // edges per binning block (16 per thread @256) - proven

// ---------------------------------------------------------------------------
// K1: fused. Blocks [0,nbin): counting-sort binning (R6-proven).
//     Blocks [nbin,...): zproj, 16 lanes per node.
__global__ void k1_zproj_bin(const float* __restrict__ x,
                             const float* __restrict__ WB,     // [3][256]
                             float4* __restrict__ z4, int N,
                             const int* __restrict__ idx, int E, int nsample,
                             unsigned* __restrict__ recs, int* __restrict__ gcur,
                             int nbin) {
    __shared__ int s_hist[NB];
    __shared__ int s_lbase[NB];
    __shared__ int s_base[NB];
    __shared__ int s_rank[NB];
    __shared__ int s_wsum[4];
    __shared__ int s_nz;
    __shared__ unsigned s_buf[CHUNK];

    if ((int)blockIdx.x < nbin) {
        // ---- bin branch ----
        if (threadIdx.x == 0) s_nz = 0;
        { int t = threadIdx.x; s_hist[t] = 0; s_rank[t] = 0; }   // blockDim == NB
        __syncthreads();
        int nz = 0;
        for (int i = threadIdx.x; i < nsample; i += 256) nz |= idx[2 * i + 1];
        if (nz) s_nz = 1;                    // benign race
        __syncthreads();
        const int stride = (s_nz == 0) ? 2 : 1;
        const int* rowp = idx;
        const int* colp = idx + (size_t)E * stride;
        const int e0 = blockIdx.x * CHUNK;

        int er[16], ec[16];
        #pragma unroll
        for (int k = 0; k < 16; ++k) {
            int e = e0 + k * 256 + (int)threadIdx.x;
            er[k] = 0; ec[k] = 0;            // sentinel r==c -> skipped
            if (e < E) {
                if (stride == 2) {
                    er[k] = reinterpret_cast<const int2*>(rowp)[e].x;
                    ec[k] = reinterpret_cast<const int2*>(colp)[e].x;
                } else {
                    er[k] = rowp[e];
                    ec[k] = colp[e];
                }
            }
        }
        #pragma unroll
        for (int k = 0; k < 16; ++k)
            if (er[k] != ec[k]) atomicAdd(&s_hist[ec[k] / BS], 1);
        __syncthreads();

        // 256-entry exclusive scan: 4-wave shuffle scan + cross-wave offsets
        {
            int t = threadIdx.x;             // == bucket id
            int v = s_hist[t];
            int incl = v;
            #pragma unroll
            for (int d = 1; d < 64; d <<= 1) {
                int o = __shfl_up(incl, d);
                if ((t & 63) >= d) incl += o;
            }
            if ((t & 63) == 63) s_wsum[t >> 6] = incl;
            __syncthreads();
            int woff = 0;
            #pragma unroll
            for (int w = 0; w < 4; ++w) if (w < (t >> 6)) woff += s_wsum[w];
            s_lbase[t] = woff + incl - v;
            s_base[t]  = v ? atomicAdd(&gcur[t], v) : 0;
        }
        __syncthreads();

        #pragma unroll
        for (int k = 0; k < 16; ++k) {
            if (er[k] != ec[k]) {
                int b = ec[k] / BS;
                int pos = s_lbase[b] + atomicAdd(&s_rank[b], 1);
                s_buf[pos] = ((unsigned)er[k] << 9) | (unsigned)(ec[k] - b * BS);
            }
        }
        __syncthreads();

        int total = s_lbase[NB - 1] + s_hist[NB - 1];
        for (int i = threadIdx.x; i < total; i += 256) {
            int lo = 0, hi = NB - 1;         // largest b with lbase[b] <= i
            #pragma unroll
            for (int s = 0; s < 8; ++s) {
                int mid = (lo + hi + 1) >> 1;
                if (s_lbase[mid] <= i) lo = mid; else hi = mid - 1;
            }
            int rel = s_base[lo] + (i - s_lbase[lo]);
            if (rel < CAP2)
                recs[(size_t)lo * CAP2 + rel] = s_buf[i];
        }
        return;
    }

    // ---- zproj branch: 16 lanes per node ----
    int gtid = (blockIdx.x - nbin) * blockDim.x + threadIdx.x;
    int node = gtid >> 4;
    int l = threadIdx.x & 15;
    if (node >= N) return;

    const float4* xr = reinterpret_cast<const float4*>(x + (size_t)node * IN_DIM);
    const float4* wb0 = reinterpret_cast<const float4*>(WB);
    const float4* wb1 = reinterpret_cast<const float4*>(WB + IN_DIM);
    const float4* wb2 = reinterpret_cast<const float4*>(WB + 2 * IN_DIM);

    float p0 = 0.f, p1 = 0.f, p2 = 0.f;
    #pragma unroll
    for (int j = 0; j < 4; ++j) {
        int c = j * 16 + l;                  // group reads 256B contiguous
        float4 xv = xr[c];
        float4 w0 = wb0[c];
        float4 w1 = wb1[c];
        float4 w2 = wb2[c];
        p0 += xv.x * w0.x + xv.y * w0.y + xv.z * w0.z + xv.w * w0.w;
        p1 += xv.x * w1.x + xv.y * w1.y + xv.z * w1.z + xv.w * w1.w;
        p2 += xv.x * w2.x + xv.y * w2.y + xv.z * w2.z + xv.w * w2.w;
    }
    #pragma unroll
    for (int m = 8; m > 0; m >>= 1) {        // reduce within 16-lane group
        p0 += __shfl_xor(p0, m);
        p1 += __shfl_xor(p1, m);
        p2 += __shfl_xor(p2, m);
    }
    if (l == 0) z4[node] = make_float4(p0, p1, p2, 0.0f);
}

// ---------------------------------------------------------------------------
// K2: one block per sub-bucket: degree histogram from slab, then
// zw[n] = (dinv*z, dinv) with dinv = rsqrt(deg+1).
__global__ void __launch_bounds__(512) k2_zw(
        const unsigned* __restrict__ recs, const int* __restrict__ gcur,
        const float4* __restrict__ z4, float4* __restrict__ zw, int N) {
    __shared__ int s_deg[BS];
    int b = blockIdx.x;
    for (int j = threadIdx.x; j < BS; j += 512) s_deg[j] = 0;
    __syncthreads();
    int cnt = gcur[b]; if (cnt > CAP2) cnt = CAP2;
    const unsigned* rb = recs + (size_t)b * CAP2;
    for (int i = threadIdx.x; i < cnt; i += 512)
        atomicAdd(&s_deg[rb[i] & 511u], 1);
    __syncthreads();
    for (int j = threadIdx.x; j < BS; j += 512) {
        int n = b * BS + j;
        if (n >= N) break;
        float di = rsqrtf((float)s_deg[j] + 1.0f);
        float4 zn = z4[n];
        zw[n] = make_float4(di * zn.x, di * zn.y, di * zn.z, di);
    }
}

// ---------------------------------------------------------------------------
// K3: one block per sub-bucket. Scan OWN slab only, LDS-accumulate, fused
// epilogue: a = zw[n].w*(sum + zw[n].xyz); out[n][:] = a . W_A + bias.
__global__ void __launch_bounds__(1024) k3_aggout(
        const unsigned* __restrict__ recs, const int* __restrict__ gcur,
        const float4* __restrict__ zw,
        const float* __restrict__ WA,   // [64][3]
        const float* __restrict__ bias,
        float* __restrict__ out, int N) {
    __shared__ float s_agg[BS * 3];
    __shared__ float s_wa0[64], s_wa1[64], s_wa2[64], s_bb[64];
    int b = blockIdx.x;

    for (int j = threadIdx.x; j < BS * 3; j += 1024) s_agg[j] = 0.0f;
    if (threadIdx.x < 64) {
        int j = threadIdx.x;
        s_wa0[j] = WA[j * 3 + 0];
        s_wa1[j] = WA[j * 3 + 1];
        s_wa2[j] = WA[j * 3 + 2];
        s_bb[j]  = bias[j];
    }
    __syncthreads();

    int cnt = gcur[b]; if (cnt > CAP2) cnt = CAP2;
    const unsigned* rb = recs + (size_t)b * CAP2;
    for (int i = threadIdx.x; i < cnt; i += 1024) {
        unsigned rc = rb[i];
        int cl = (int)(rc & 511u);
        float4 zr = zw[rc >> 9];
        atomicAdd(&s_agg[cl * 3 + 0], zr.x);
        atomicAdd(&s_agg[cl * 3 + 1], zr.y);
        atomicAdd(&s_agg[cl * 3 + 2], zr.z);
    }
    __syncthreads();

    if (threadIdx.x < BS) {
        int n = b * BS + (int)threadIdx.x;
        if (n < N) {
            float4 zn = zw[n];
            float di = zn.w;
            s_agg[threadIdx.x * 3 + 0] = di * (s_agg[threadIdx.x * 3 + 0] + zn.x);
            s_agg[threadIdx.x * 3 + 1] = di * (s_agg[threadIdx.x * 3 + 1] + zn.y);
            s_agg[threadIdx.x * 3 + 2] = di * (s_agg[threadIdx.x * 3 + 2] + zn.z);
        }
    }
    __syncthreads();

    for (int i = threadIdx.x; i < BS * 16; i += 1024) {
        int nl = i >> 4, j4 = (i & 15) << 2;
        int n = b * BS + nl;
        if (n >= N) continue;
        float a0 = s_agg[nl * 3 + 0], a1 = s_agg[nl * 3 + 1], a2 = s_agg[nl * 3 + 2];
        float4 o;
        o.x = a0 * s_wa0[j4+0] + a1 * s_wa1[j4+0] + a2 * s_wa2[j4+0] + s_bb[j4+0];
        o.y = a0 * s_wa0[j4+1] + a1 * s_wa1[j4+1] + a2 * s_wa2[j4+1] + s_bb[j4+1];
        o.z = a0 * s_wa0[j4+2] + a1 * s_wa1[j4+2] + a2 * s_wa2[j4+2] + s_bb[j4+2];
        o.w = a0 * s_wa0[j4+3] + a1 * s_wa1[j4+3] + a2 * s_wa2[j4+3] + s_bb[j4+3];
        *reinterpret_cast<float4*>(out + (size_t)n * OUT_DIM + j4) = o;
    }
}

// ---------------------------------------------------------------------------
// Fallback (R1 path, shape-robust): detect + global-atomic deg/scatter + out.
__global__ void detect_kernel(const int* __restrict__ idx, int nsample, int* flag) {
    __shared__ int s_nz;
    if (threadIdx.x == 0) s_nz = 0;
    __syncthreads();
    int nz = 0;
    for (int i = threadIdx.x; i < nsample; i += blockDim.x) nz |= idx[2 * i + 1];
    if (nz) s_nz = 1;
    __syncthreads();
    if (threadIdx.x == 0) *flag = (s_nz == 0) ? 1 : 0;
}
__global__ void deg_kernel(const int* __restrict__ idx, int E,
                           const int* __restrict__ flag, float* __restrict__ deg) {
    int stride = (*flag) ? 2 : 1;
    const int* rowp = idx;
    const int* colp = idx + (size_t)E * stride;
    int step = gridDim.x * blockDim.x;
    for (int e = blockIdx.x * blockDim.x + threadIdx.x; e < E; e += step) {
        int r = rowp[(size_t)e * stride];
        int c = colp[(size_t)e * stride];
        if (r != c) atomicAdd(&deg[c], 1.0f);
    }
}
__global__ void dinv_self_kernel(const float4* __restrict__ z4, const float* __restrict__ deg,
                                 float* __restrict__ dinv, float* __restrict__ agg, int N) {
    int n = blockIdx.x * blockDim.x + threadIdx.x;
    if (n >= N) return;
    float d = deg[n] + 1.0f;
    float di = rsqrtf(d);
    dinv[n] = di;
    float w = 1.0f / d;
    float4 zn = z4[n];
    agg[(size_t)n * 3 + 0] = w * zn.x;
    agg[(size_t)n * 3 + 1] = w * zn.y;
    agg[(size_t)n * 3 + 2] = w * zn.z;
}
__global__ void scatter_kernel(const int* __restrict__ idx, int E,
                               const int* __restrict__ flag,
                               const float4* __restrict__ z4,
                               const float* __restrict__ dinv,
                               float* __restrict__ agg) {
    int stride = (*flag) ? 2 : 1;
    const int* rowp = idx;
    const int* colp = idx + (size_t)E * stride;
    int step = gridDim.x * blockDim.x;
    for (int e = blockIdx.x * blockDim.x + threadIdx.x; e < E; e += step) {
        int r = rowp[(size_t)e * stride];
        int c = colp[(size_t)e * stride];
        if (r != c) {
            float w = dinv[r] * dinv[c];
            float4 zr = z4[r];
            atomicAdd(&agg[(size_t)c * 3 + 0], w * zr.x);
            atomicAdd(&agg[(size_t)c * 3 + 1], w * zr.y);
            atomicAdd(&agg[(size_t)c * 3 + 2], w * zr.z);
        }
    }
}
__global__ void out_kernel(const float* __restrict__ agg,
                           const float* __restrict__ WA,
                           const float* __restrict__ bias,
                           float* __restrict__ out, int N) {
    int t = blockIdx.x * blockDim.x + threadIdx.x;
    int n = t >> 6;
    int j = t & 63;
    if (n >= N) return;
    float a0 = agg[(size_t)n * 3 + 0];
    float a1 = agg[(size_t)n * 3 + 1];
    float a2 = agg[(size_t)n * 3 + 2];
    out[(size_t)n * OUT_DIM + j] =
        a0 * WA[j * 3 + 0] + a1 * WA[j * 3 + 1] + a2 * WA[j * 3 + 2] + bias[j];
}

extern "C" void kernel_launch(void* const* d_in, const int* in_sizes, int n_in,
                              void* d_out, int out_size, void* d_ws, size_t ws_size,
                              hipStream_t stream) {
    const float* x    = (const float*)d_in[0];
    const int*   idx  = (const int*)d_in[1];
    const float* WB   = (const float*)d_in[2];
    const float* WA   = (const float*)d_in[3];
    const float* bias = (const float*)d_in[4];
    float* out = (float*)d_out;

    const int N = in_sizes[0] / IN_DIM;     // 100000
    const int E = in_sizes[1] / 2;          // 1600000

    auto align256 = [](size_t o) { return (o + 255) & ~(size_t)255; };
    char* ws = (char*)d_ws;
    size_t off = 0;
    int*    flag = (int*)(ws + off);    off = align256(off + sizeof(int));
    int*    gcur = (int*)(ws + off);    off = align256(off + NB * sizeof(int));
    float4* z4   = (float4*)(ws + off); off = align256(off + (size_t)N * sizeof(float4));
    float4* zw   = (float4*)(ws + off); off = align256(off + (size_t)N * sizeof(float4));
    float*  dinv = (float*)(ws + off);  off = align256(off + (size_t)N * sizeof(float));
    unsigned* recs = (unsigned*)(ws + off); off = align256(off + (size_t)NB * CAP2 * sizeof(unsigned));
    // fallback reuses fast-path regions
    float* degF = (float*)zw;
    float* aggF = (float*)recs;            // N*3 floats fit in recs region (8MB)

    const bool fast = (N <= NB * BS) && (N < (1 << 23)) && (ws_size >= off);

    int nsample = E < 1024 ? E : 1024;

    if (fast) {
        hipMemsetAsync(gcur, 0, NB * sizeof(int), stream);
        int nbin = (E + CHUNK - 1) / CHUNK;
        int nzp  = (N + 15) / 16;           // 16 nodes per 256-thread block
        k1_zproj_bin<<<nbin + nzp, 256, 0, stream>>>(x, WB, z4, N, idx, E, nsample,
                                                     recs, gcur, nbin);
        k2_zw<<<NB, 512, 0, stream>>>(recs, gcur, z4, zw, N);
        k3_aggout<<<NB, 1024, 0, stream>>>(recs, gcur, zw, WA, bias, out, N);
    } else {
        detect_kernel<<<1, 256, 0, stream>>>(idx, nsample, flag);
        k1_zproj_bin<<<(N + 15) / 16, 256, 0, stream>>>(x, WB, z4, N, idx, E, nsample,
                                                        (unsigned*)aggF, gcur, 0);
        hipMemsetAsync(degF, 0, (size_t)N * sizeof(float), stream);
        deg_kernel<<<2048, 256, 0, stream>>>(idx, E, flag, degF);
        dinv_self_kernel<<<(N + 255) / 256, 256, 0, stream>>>(z4, degF, dinv, aggF, N);
        scatter_kernel<<<2048, 256, 0, stream>>>(idx, E, flag, z4, dinv, aggF);
        long long total = (long long)N * OUT_DIM;
        out_kernel<<<(int)((total + 255) / 256), 256, 0, stream>>>(aggF, WA, bias, out, N);
    }
}